// Round 10
// baseline (464.115 us; speedup 1.0000x reference)
//
#include <hip/hip_runtime.h>
#include <hip/hip_cooperative_groups.h>
#include <math.h>

namespace cg = cooperative_groups;

#define H 256
#define W 256
#define HW (H * W)
#define CH 24
#define NK 63
#define PXS 40          // t1 per-pixel stride in shorts (80 B)
#define TBS 32          // tbt per-pixel stride in shorts (64 B)
#define KSTEPS 25       // K = 25 taps * 32 (24 ch + 8 zero-pad)
#define T3S 26          // t3 per-pixel stride in floats

typedef short v8s __attribute__((ext_vector_type(8)));
typedef short v4s __attribute__((ext_vector_type(4)));
typedef float v4f __attribute__((ext_vector_type(4)));

// ---------------- LDS phase union ---------------------------------------------
struct SmemA {
    float ws0[CH * NK];      // [0, 6048)
    float ws1[CH * NK];      // [6048, 12096)
    float xs[256];           // [12096, 13120)
    short t1[144 * PXS];     // [13120, 24640)
};
struct SmemB {
    float ws0[CH * NK];      // [0, 6048)   persists from phase A
    short tbt[256 * TBS];    // [6048, 22432)  overlays ws1/xs/t1 head
    float t3[144 * T3S];     // [22432, 37408)
};
union __align__(16) SmemU { SmemA a; SmemB b; };

// ---------------- analytic RBF ------------------------------------------------
struct RbfCtx {
    float m0, istep, c2a, ahalf, dfac;
    float G1, G2, G3, G4;
};
__device__ __forceinline__ RbfCtx make_ctx(const float* __restrict__ mean) {
    RbfCtx c;
    c.m0 = mean[0];
    float m62 = mean[NK - 1];
    float step = (m62 - c.m0) * (1.f / (float)(NK - 1));
    c.istep = (float)(NK - 1) / (m62 - c.m0);
    float a = step * step * (1.f / 200.f);
    c.c2a = 2.f * a;
    c.ahalf = a;
    c.dfac = -step * 0.01f;
    c.G1 = __expf(-a);
    c.G2 = __expf(-4.f * a);
    c.G3 = __expf(-9.f * a);
    c.G4 = __expf(-16.f * a);
    return c;
}

template<bool DER>
__device__ __forceinline__ float rbf_eval(float v, const float* __restrict__ wrow,
                                          const RbfCtx& c) {
    float t = (v - c.m0) * c.istep;
    float kcf = floorf(t + 0.5f);
    kcf = fminf(fmaxf(kcf, 4.f), (float)(NK - 5));
    int kc = (int)kcf;
    float f = t - kcf;
    f = fminf(fmaxf(f, -12.f), 12.f);
    float g  = c.c2a * f;
    float E1 = __expf(g), R1 = __expf(-g);
    float E2 = E1 * E1, R2 = R1 * R1;
    float gpm4 = c.G4 * R2 * R2, gpm3 = c.G3 * R2 * R1, gpm2 = c.G2 * R2, gpm1 = c.G1 * R1;
    float gpp1 = c.G1 * E1, gpp2 = c.G2 * E2, gpp3 = c.G3 * E2 * E1, gpp4 = c.G4 * E2 * E2;
    const float* p = wrow + (kc - 4);
    float m_m4 = p[0] * gpm4, m_m3 = p[1] * gpm3, m_m2 = p[2] * gpm2, m_m1 = p[3] * gpm1;
    float m_0  = p[4];
    float m_p1 = p[5] * gpp1, m_p2 = p[6] * gpp2, m_p3 = p[7] * gpp3, m_p4 = p[8] * gpp4;
    float S0 = ((m_m4 + m_m3) + (m_m2 + m_m1)) + m_0 + ((m_p1 + m_p2) + (m_p3 + m_p4));
    float base = __expf(-c.ahalf * f * f);
    if (!DER) return base * S0;
    float S1 = 0.f;
    S1 = fmaf(m_m4, -4.f, S1); S1 = fmaf(m_m3, -3.f, S1);
    S1 = fmaf(m_m2, -2.f, S1); S1 = fmaf(m_m1, -1.f, S1);
    S1 = fmaf(m_p1,  1.f, S1); S1 = fmaf(m_p2,  2.f, S1);
    S1 = fmaf(m_p3,  3.f, S1); S1 = fmaf(m_p4,  4.f, S1);
    return c.dfac * base * fmaf(f, S0, -S1);
}

__device__ __forceinline__ short f2bf(float v) {
    unsigned u = __float_as_uint(v);
    u += 0x7fff + ((u >> 16) & 1);
    return (short)(u >> 16);
}

// ---------------- phase P: norms + A-fragment pack (blocks 0..24) -------------
__device__ __forceinline__ void do_prep(int bid, int tid,
        const float* __restrict__ f0, const float* __restrict__ f1,
        float* __restrict__ f0n, float* __restrict__ f0t,
        v8s* __restrict__ abuf, float* red) {
    float s1 = 0.f;
    for (int i = tid; i < 14400; i += 256) s1 += f1[i] * f1[i];
    red[tid] = s1; __syncthreads();
    for (int off = 128; off; off >>= 1) { if (tid < off) red[tid] += red[tid + off]; __syncthreads(); }
    float inv1 = 1.f / sqrtf(red[0]);
    __syncthreads();
    if (bid == 0) {
        float s0 = 0.f;
        for (int i = tid; i < 600; i += 256) s0 += f0[i] * f0[i];
        red[tid] = s0; __syncthreads();
        for (int off = 128; off; off >>= 1) { if (tid < off) red[tid] += red[tid + off]; __syncthreads(); }
        float inv0 = 1.f / sqrtf(red[0]);
        for (int i = tid; i < 600; i += 256) {
            int c = i / 25, k = i % 25;
            f0n[i] = f0[i] * inv0;
            f0t[i] = f0[c * 25 + (24 - k)] * inv0;
        }
    }
    int gid = bid * 256 + tid;
    int lane = gid & 63;
    int rest = gid >> 6;          // 0..99
    int s = rest % KSTEPS;
    int md = rest / KSTEPS;       // 0..3
    int mode = md >> 1, m = md & 1;
    int o = m * 16 + (lane & 15);
    v8s av;
    #pragma unroll
    for (int j = 0; j < 8; ++j) {
        int c = 8 * (lane >> 4) + j;
        float wv = 0.f;
        if (o < CH && c < CH) {
            wv = (mode == 0) ? f1[(o * CH + c) * 25 + s]
                             : f1[(c * CH + o) * 25 + (24 - s)];
            wv *= inv1;
        }
        av[j] = f2bf(wv);
    }
    abuf[gid] = av;
}

// ---------------- phase A: conv1+rbf0 -> conv2 MFMA + rbf1 --------------------
__device__ __forceinline__ void do_phaseA(int x0, int y0, int tid,
        const float* __restrict__ x, const float* __restrict__ f0n,
        const v8s* __restrict__ abuf, const float* __restrict__ aw0,
        const float* __restrict__ aw1, const RbfCtx& ctx,
        short* __restrict__ tb, SmemA& sm) {
    {
        int r = tid >> 4, cL = tid & 15;
        int gy = min(max(y0 + r - 4, 0), H - 1);
        int gx = min(max(x0 + cL - 4, 0), W - 1);
        sm.xs[tid] = x[gy * W + gx];
    }
    for (int i = tid; i < CH * NK; i += 256) { sm.ws0[i] = aw0[i]; sm.ws1[i] = aw1[i]; }
    __syncthreads();

    if (tid < 144) {
        int yi = (tid * 5462) >> 16;        // tid / 12
        int xi = tid - yi * 12;
        int sy = min(max(y0 + yi - 2, 0), H - 1);
        int sx = min(max(x0 + xi - 2, 0), W - 1);
        int iy[5], ix[5];
        #pragma unroll
        for (int u = 0; u < 5; ++u) {
            iy[u] = min(max(sy + u - 2, 0), H - 1) - (y0 - 4);
            ix[u] = min(max(sx + u - 2, 0), W - 1) - (x0 - 4);
        }
        float in_[25];
        #pragma unroll
        for (int u = 0; u < 5; ++u)
            #pragma unroll
            for (int v = 0; v < 5; ++v) in_[u * 5 + v] = sm.xs[iy[u] * 16 + ix[v]];
        #pragma unroll 1
        for (int og = 0; og < 3; ++og) {
            v8s pk;
            #pragma unroll
            for (int oj = 0; oj < 8; ++oj) {
                int o = og * 8 + oj;
                float a = 0.f;
                #pragma unroll
                for (int k = 0; k < 25; ++k) a = fmaf(in_[k], f0n[o * 25 + k], a);
                pk[oj] = f2bf(rbf_eval<false>(a, sm.ws0 + o * NK, ctx));
            }
            *(v8s*)&sm.t1[tid * PXS + og * 8] = pk;
        }
        v8s z = {0,0,0,0,0,0,0,0};
        *(v8s*)&sm.t1[tid * PXS + 24] = z;
    }
    __syncthreads();

    int lane = tid & 63, wv_ = tid >> 6;
    int p = lane & 15, q = lane >> 4;
    int row = (wv_ * 16 + p) >> 3, col = p & 7;
    const short* bbase = &sm.t1[(row * 12 + col) * PXS + q * 8];
    v4f a0v = {0.f,0.f,0.f,0.f}, a1v = {0.f,0.f,0.f,0.f};
    #pragma unroll
    for (int s = 0; s < KSTEPS; ++s) {
        const int u = s / 5, v = s % 5;
        v8s b   = *(const v8s*)&bbase[(u * 12 + v) * PXS];
        v8s af0 = abuf[s * 64 + lane];
        v8s af1 = abuf[1600 + s * 64 + lane];
        a0v = __builtin_amdgcn_mfma_f32_16x16x32_bf16(af0, b, a0v, 0, 0, 0);
        a1v = __builtin_amdgcn_mfma_f32_16x16x32_bf16(af1, b, a1v, 0, 0, 0);
    }
    int pix = (y0 + row) * W + (x0 + col);
    v4s st;
    #pragma unroll
    for (int j = 0; j < 4; ++j)
        st[j] = f2bf(rbf_eval<false>(a0v[j], sm.ws1 + (q * 4 + j) * NK, ctx));
    *(v4s*)&tb[pix * 24 + q * 4] = st;
    if (q < 2) {
        #pragma unroll
        for (int j = 0; j < 4; ++j)
            st[j] = f2bf(rbf_eval<false>(a1v[j], sm.ws1 + (16 + q * 4 + j) * NK, ctx));
        *(v4s*)&tb[pix * 24 + 16 + q * 4] = st;
    }
}

// ---------------- phase B: convT2 MFMA + rbf' -> convT1 + final ---------------
__device__ __forceinline__ void do_phaseB(int x0, int y0, int tid,
        const short* __restrict__ tb, const v8s* __restrict__ abuf,
        const float* __restrict__ f0t, const float* __restrict__ aw0,
        const float* __restrict__ x, const float* __restrict__ y,
        const float* __restrict__ lamp, const RbfCtx& ctx,
        float* __restrict__ out, SmemB& sm) {
    {
        int r = tid >> 4, cL = tid & 15;
        int gy = y0 + r - 4, gx = x0 + cL - 4;
        v8s z = {0,0,0,0,0,0,0,0};
        if (gy >= 0 && gy < H && gx >= 0 && gx < W) {
            const v8s* src = (const v8s*)&tb[(gy * W + gx) * 24];
            *(v8s*)&sm.tbt[tid * TBS]      = src[0];
            *(v8s*)&sm.tbt[tid * TBS + 8]  = src[1];
            *(v8s*)&sm.tbt[tid * TBS + 16] = src[2];
        } else {
            *(v8s*)&sm.tbt[tid * TBS]      = z;
            *(v8s*)&sm.tbt[tid * TBS + 8]  = z;
            *(v8s*)&sm.tbt[tid * TBS + 16] = z;
        }
        *(v8s*)&sm.tbt[tid * TBS + 24] = z;
    }
    for (int i = tid; i < CH * NK; i += 256) sm.ws0[i] = aw0[i];
    __syncthreads();

    int lane = tid & 63, wv_ = tid >> 6;
    int p = lane & 15, q = lane >> 4;
    const v8s* ap = abuf + 3200;
    int base[3], frow[3], fcol[3];
    bool valid[3];
    #pragma unroll
    for (int g = 0; g < 3; ++g) {
        int tIdx = wv_ * 3 + g;
        valid[g] = (tIdx <= 8);
        int tc = valid[g] ? tIdx : 8;
        int f = tc * 16 + p;
        int r_ = (f * 5462) >> 16;
        frow[g] = r_; fcol[g] = f - r_ * 12;
        base[g] = (r_ * 16 + fcol[g]) * TBS + q * 8;
    }
    v4f acc0[3], acc1[3];
    #pragma unroll
    for (int g = 0; g < 3; ++g) { acc0[g] = (v4f){0.f,0.f,0.f,0.f}; acc1[g] = (v4f){0.f,0.f,0.f,0.f}; }
    #pragma unroll
    for (int s = 0; s < KSTEPS; ++s) {
        const int off = ((s / 5) * 16 + (s % 5)) * TBS;
        v8s af0 = ap[s * 64 + lane];
        v8s af1 = ap[1600 + s * 64 + lane];
        #pragma unroll
        for (int g = 0; g < 3; ++g) {
            v8s b = *(const v8s*)&sm.tbt[base[g] + off];
            acc0[g] = __builtin_amdgcn_mfma_f32_16x16x32_bf16(af0, b, acc0[g], 0, 0, 0);
            acc1[g] = __builtin_amdgcn_mfma_f32_16x16x32_bf16(af1, b, acc1[g], 0, 0, 0);
        }
    }
    #pragma unroll
    for (int g = 0; g < 3; ++g) {
        if (valid[g]) {
            int f = (wv_ * 3 + g) * 16 + p;
            int gy = y0 + frow[g] - 2, gx = x0 + fcol[g] - 2;
            bool inimg = (gy >= 0 && gy < H && gx >= 0 && gx < W);
            #pragma unroll
            for (int j = 0; j < 4; ++j)
                sm.t3[f * T3S + q * 4 + j] =
                    inimg ? rbf_eval<true>(acc0[g][j], sm.ws0 + (q * 4 + j) * NK, ctx) : 0.f;
            if (q < 2) {
                #pragma unroll
                for (int j = 0; j < 4; ++j)
                    sm.t3[f * T3S + 16 + q * 4 + j] =
                        inimg ? rbf_eval<true>(acc1[g][j], sm.ws0 + (16 + q * 4 + j) * NK, ctx) : 0.f;
            }
        }
    }
    __syncthreads();

    float* red = (float*)sm.tbt;
    int g = __builtin_amdgcn_readfirstlane(tid >> 6);
    int px = tid & 63, pr = px >> 3, pc = px & 7;
    float a = 0.f;
    #pragma unroll 1
    for (int cp = 0; cp < 3; ++cp) {
        int c = g * 6 + cp * 2;
        const float* fb0 = f0t + c * 25;
        const float* fb1 = f0t + (c + 1) * 25;
        #pragma unroll
        for (int u = 0; u < 5; ++u)
            #pragma unroll
            for (int v = 0; v < 5; ++v) {
                float2 tp = *(const float2*)&sm.t3[((pr + u) * 12 + (pc + v)) * T3S + c];
                a = fmaf(tp.x, fb0[u * 5 + v], a);
                a = fmaf(tp.y, fb1[u * 5 + v], a);
            }
    }
    red[tid] = a;
    __syncthreads();
    if (tid < 64) {
        float tot = red[tid] + red[64 + tid] + red[128 + tid] + red[192 + tid];
        int pix = (y0 + pr) * W + (x0 + pc);
        float elam = __expf(lamp[0]);
        float xv = x[pix], yv = y[pix];
        out[pix] = xv - (tot + elam * (xv - yv));
    }
}

// ---------------- single cooperative kernel -----------------------------------
__global__ __launch_bounds__(256, 4) void k_all(
        const float* __restrict__ x, const float* __restrict__ y,
        const float* __restrict__ f0, const float* __restrict__ f1,
        const float* __restrict__ aw0, const float* __restrict__ aw1,
        const float* __restrict__ mean, const float* __restrict__ lamp,
        float* __restrict__ out, float* __restrict__ f0n,
        float* __restrict__ f0t, v8s* __restrict__ abuf,
        short* __restrict__ tb) {
    __shared__ SmemU sm;
    cg::grid_group gg = cg::this_grid();
    int tid = threadIdx.x;
    int bid = blockIdx.x;
    if (bid < 25) do_prep(bid, tid, f0, f1, f0n, f0t, abuf, (float*)&sm);
    __threadfence();
    gg.sync();
    RbfCtx ctx = make_ctx(mean);
    int x0 = (bid & 31) * 8, y0 = (bid >> 5) * 8;
    do_phaseA(x0, y0, tid, x, f0n, abuf, aw0, aw1, ctx, tb, sm.a);
    __threadfence();
    gg.sync();
    do_phaseB(x0, y0, tid, tb, abuf, f0t, aw0, x, y, lamp, ctx, out, sm.b);
}

// ---------------- fallback path (3 kernels) ------------------------------------
__global__ void k_prep(const float* __restrict__ f0, const float* __restrict__ f1,
                       float* __restrict__ f0n, float* __restrict__ f0t,
                       v8s* __restrict__ abuf) {
    __shared__ float red[256];
    do_prep(blockIdx.x, threadIdx.x, f0, f1, f0n, f0t, abuf, red);
}
__global__ __launch_bounds__(256, 4) void k_fuseA(const float* __restrict__ x,
        const float* __restrict__ f0n, const v8s* __restrict__ abuf,
        const float* __restrict__ mean, const float* __restrict__ aw0,
        const float* __restrict__ aw1, short* __restrict__ tb) {
    __shared__ SmemU sm;
    RbfCtx ctx = make_ctx(mean);
    do_phaseA(blockIdx.x * 8, blockIdx.y * 8, threadIdx.x, x, f0n, abuf, aw0, aw1, ctx, tb, sm.a);
}
__global__ __launch_bounds__(256, 4) void k_fuseB(const short* __restrict__ tb,
        const v8s* __restrict__ abuf, const float* __restrict__ f0t,
        const float* __restrict__ mean, const float* __restrict__ aw0,
        const float* __restrict__ x, const float* __restrict__ y,
        const float* __restrict__ lamp, float* __restrict__ out) {
    __shared__ SmemU sm;
    RbfCtx ctx = make_ctx(mean);
    do_phaseB(blockIdx.x * 8, blockIdx.y * 8, threadIdx.x, tb, abuf, f0t, aw0, x, y, lamp, ctx, out, sm.b);
}

extern "C" void kernel_launch(void* const* d_in, const int* in_sizes, int n_in,
                              void* d_out, int out_size, void* d_ws, size_t ws_size,
                              hipStream_t stream) {
    const float* x    = (const float*)d_in[0];
    const float* y    = (const float*)d_in[1];
    const float* f0   = (const float*)d_in[3];
    const float* f1   = (const float*)d_in[4];
    const float* aw0  = (const float*)d_in[5];
    const float* aw1  = (const float*)d_in[6];
    const float* mean = (const float*)d_in[7];
    const float* lamp = (const float*)d_in[8];
    float* out = (float*)d_out;

    float* w   = (float*)d_ws;
    float* f0n = w;                  // 600
    float* f0t = w + 640;            // 600
    v8s*  abuf = (v8s*)(w + 1536);   // 6400 * 16 B
    short* tb  = (short*)(w + 32768);

    void* args[] = {(void*)&x, (void*)&y, (void*)&f0, (void*)&f1,
                    (void*)&aw0, (void*)&aw1, (void*)&mean, (void*)&lamp,
                    (void*)&out, (void*)&f0n, (void*)&f0t, (void*)&abuf,
                    (void*)&tb};
    hipError_t e = hipLaunchCooperativeKernel((void*)k_all, dim3(1024), dim3(256),
                                              args, 0, stream);
    if (e != hipSuccess) {
        dim3 grid(W / 8, H / 8);
        k_prep<<<25, 256, 0, stream>>>(f0, f1, f0n, f0t, abuf);
        k_fuseA<<<grid, 256, 0, stream>>>(x, f0n, abuf, mean, aw0, aw1, tb);
        k_fuseB<<<grid, 256, 0, stream>>>(tb, abuf, f0t, mean, aw0, x, y, lamp, out);
    }
}

// Round 11
// 98.213 us; speedup vs baseline: 4.7256x; 4.7256x over previous
//
#include <hip/hip_runtime.h>
#include <math.h>

#define H 256
#define W 256
#define HW (H * W)
#define CH 24
#define NK 63
#define KSTEPS 25       // K = 25 taps * 32 (24 ch + 8 zero-pad in A-frags)
#define T3S 26          // t3 per-pixel stride in floats

typedef short v8s __attribute__((ext_vector_type(8)));
typedef short v4s __attribute__((ext_vector_type(4)));
typedef float v4f __attribute__((ext_vector_type(4)));

// ---------------- LDS: phase-union, 43.6 KB ------------------------------------
struct Smem {
    float ws0[CH * NK];          // phase1 + phase3 (rbf0 / rbf_der weights)
    float ws1[CH * NK];          // phase2 epilogue; red[] overlays in phase4
    union {
        short t1[400 * 24 + 8];  // 20x20 conv1+rbf0 tile (+zero pad), ph1->ph2
        float t3[144 * T3S];     // 12x12 rbf_der tile, ph3->ph4
    } u1;
    union {
        float xs[24 * 24];       // x window, ph1
        short tbt[256 * 24 + 8]; // 16x16 tb tile (+zero pad), ph2->ph3
    } u2;
};

// ---------------- analytic RBF --------------------------------------------------
struct RbfCtx {
    float m0, istep, c2a, ahalf, dfac;
    float G1, G2, G3, G4;
};
__device__ __forceinline__ RbfCtx make_ctx(const float* __restrict__ mean) {
    RbfCtx c;
    c.m0 = mean[0];
    float m62 = mean[NK - 1];
    float step = (m62 - c.m0) * (1.f / (float)(NK - 1));
    c.istep = (float)(NK - 1) / (m62 - c.m0);
    float a = step * step * (1.f / 200.f);
    c.c2a = 2.f * a;
    c.ahalf = a;
    c.dfac = -step * 0.01f;
    c.G1 = __expf(-a);
    c.G2 = __expf(-4.f * a);
    c.G3 = __expf(-9.f * a);
    c.G4 = __expf(-16.f * a);
    return c;
}

template<bool DER>
__device__ __forceinline__ float rbf_eval(float v, const float* __restrict__ wrow,
                                          const RbfCtx& c) {
    float t = (v - c.m0) * c.istep;
    float kcf = floorf(t + 0.5f);
    kcf = fminf(fmaxf(kcf, 4.f), (float)(NK - 5));
    int kc = (int)kcf;
    float f = t - kcf;
    f = fminf(fmaxf(f, -12.f), 12.f);
    float g  = c.c2a * f;
    float E1 = __expf(g), R1 = __expf(-g);
    float E2 = E1 * E1, R2 = R1 * R1;
    float gpm4 = c.G4 * R2 * R2, gpm3 = c.G3 * R2 * R1, gpm2 = c.G2 * R2, gpm1 = c.G1 * R1;
    float gpp1 = c.G1 * E1, gpp2 = c.G2 * E2, gpp3 = c.G3 * E2 * E1, gpp4 = c.G4 * E2 * E2;
    const float* p = wrow + (kc - 4);
    float m_m4 = p[0] * gpm4, m_m3 = p[1] * gpm3, m_m2 = p[2] * gpm2, m_m1 = p[3] * gpm1;
    float m_0  = p[4];
    float m_p1 = p[5] * gpp1, m_p2 = p[6] * gpp2, m_p3 = p[7] * gpp3, m_p4 = p[8] * gpp4;
    float S0 = ((m_m4 + m_m3) + (m_m2 + m_m1)) + m_0 + ((m_p1 + m_p2) + (m_p3 + m_p4));
    float base = __expf(-c.ahalf * f * f);
    if (!DER) return base * S0;
    float S1 = 0.f;
    S1 = fmaf(m_m4, -4.f, S1); S1 = fmaf(m_m3, -3.f, S1);
    S1 = fmaf(m_m2, -2.f, S1); S1 = fmaf(m_m1, -1.f, S1);
    S1 = fmaf(m_p1,  1.f, S1); S1 = fmaf(m_p2,  2.f, S1);
    S1 = fmaf(m_p3,  3.f, S1); S1 = fmaf(m_p4,  4.f, S1);
    return c.dfac * base * fmaf(f, S0, -S1);
}

__device__ __forceinline__ short f2bf(float v) {
    unsigned u = __float_as_uint(v);
    u += 0x7fff + ((u >> 16) & 1);
    return (short)(u >> 16);
}

// ---------------- prep: norms, f0n/f0t, MFMA A-fragment pack --------------------
// abuf: [mode 2][mtile 2][kstep 25][lane 64] v8s. k = tap*32 + c (c<24, pad=0).
__global__ void k_prep(const float* __restrict__ f0, const float* __restrict__ f1,
                       float* __restrict__ f0n, float* __restrict__ f0t,
                       v8s* __restrict__ abuf) {
    __shared__ float red[256];
    int tid = threadIdx.x;
    float s1 = 0.f;
    for (int i = tid; i < 14400; i += 256) s1 += f1[i] * f1[i];
    red[tid] = s1; __syncthreads();
    for (int off = 128; off; off >>= 1) { if (tid < off) red[tid] += red[tid + off]; __syncthreads(); }
    float inv1 = 1.f / sqrtf(red[0]);
    __syncthreads();
    if (blockIdx.x == 0) {
        float s0 = 0.f;
        for (int i = tid; i < 600; i += 256) s0 += f0[i] * f0[i];
        red[tid] = s0; __syncthreads();
        for (int off = 128; off; off >>= 1) { if (tid < off) red[tid] += red[tid + off]; __syncthreads(); }
        float inv0 = 1.f / sqrtf(red[0]);
        for (int i = tid; i < 600; i += 256) {
            int c = i / 25, k = i % 25;
            f0n[i] = f0[i] * inv0;
            f0t[i] = f0[c * 25 + (24 - k)] * inv0;
        }
    }
    int gid = blockIdx.x * 256 + tid;      // 6400 jobs
    int lane = gid & 63;
    int rest = gid >> 6;                   // 0..99
    int s = rest % KSTEPS;
    int md = rest / KSTEPS;                // 0..3
    int mode = md >> 1, m = md & 1;
    int o = m * 16 + (lane & 15);
    v8s av;
    #pragma unroll
    for (int j = 0; j < 8; ++j) {
        int c = 8 * (lane >> 4) + j;
        float wv = 0.f;
        if (o < CH && c < CH) {
            wv = (mode == 0) ? f1[(o * CH + c) * 25 + s]
                             : f1[(c * CH + o) * 25 + (24 - s)];
            wv *= inv1;
        }
        av[j] = f2bf(wv);
    }
    abuf[gid] = av;
}

// ---------------- fused main: conv1+rbf0 -> conv2+rbf1 -> convT2+rbf' -> convT1 --
// 8x8 output tile, 1024 blocks, 3 blocks/CU. tb computed redundantly on 16x16 in LDS.
__global__ __launch_bounds__(256, 3) void k_main(
        const float* __restrict__ x, const float* __restrict__ y,
        const float* __restrict__ f0n, const float* __restrict__ f0t,
        const v8s* __restrict__ abuf, const float* __restrict__ mean,
        const float* __restrict__ aw0, const float* __restrict__ aw1,
        const float* __restrict__ lamp, float* __restrict__ out) {
    __shared__ Smem sm;
    int tid = threadIdx.x;
    int x0 = (blockIdx.x & 31) * 8, y0 = (blockIdx.x >> 5) * 8;

    // stage: ws0, ws1, xs (24x24 window at origin (y0-8, x0-8), clamped)
    for (int i = tid; i < CH * NK; i += 256) { sm.ws0[i] = aw0[i]; sm.ws1[i] = aw1[i]; }
    for (int i = tid; i < 576; i += 256) {
        int r = (i * 2731) >> 16;          // i / 24
        int cL = i - r * 24;
        int gy = min(max(y0 + r - 8, 0), H - 1);
        int gx = min(max(x0 + cL - 8, 0), W - 1);
        sm.u2.xs[i] = x[gy * W + gx];
    }
    RbfCtx ctx = make_ctx(mean);
    __syncthreads();

    // ---- phase 1: t1 = rbf0(conv1(x)) on 20x20 (origin y0-6, x0-6) ----
    #pragma unroll
    for (int pp = 0; pp < 2; ++pp) {
        int pos = tid + pp * 256;
        if (pos < 400) {
            int yi = (pos * 3277) >> 16;   // pos / 20
            int xi = pos - yi * 20;
            int sy = min(max(y0 + yi - 6, 0), H - 1);
            int sx = min(max(x0 + xi - 6, 0), W - 1);
            int iy[5], ix[5];
            #pragma unroll
            for (int u = 0; u < 5; ++u) {
                iy[u] = min(max(sy + u - 2, 0), H - 1) - (y0 - 8);
                ix[u] = min(max(sx + u - 2, 0), W - 1) - (x0 - 8);
            }
            float in_[25];
            #pragma unroll
            for (int u = 0; u < 5; ++u)
                #pragma unroll
                for (int v = 0; v < 5; ++v) in_[u * 5 + v] = sm.u2.xs[iy[u] * 24 + ix[v]];
            #pragma unroll 1
            for (int og = 0; og < 3; ++og) {
                v8s pk;
                #pragma unroll
                for (int oj = 0; oj < 8; ++oj) {
                    int o = og * 8 + oj;
                    float a = 0.f;
                    #pragma unroll
                    for (int k = 0; k < 25; ++k) a = fmaf(in_[k], f0n[o * 25 + k], a);
                    pk[oj] = f2bf(rbf_eval<false>(a, sm.ws0 + o * NK, ctx));
                }
                *(v8s*)&sm.u1.t1[pos * 24 + og * 8] = pk;
            }
        }
    }
    if (tid == 0) {   // zero pad after t1 (q=3 stray B-reads must be finite)
        v8s z = {0,0,0,0,0,0,0,0};
        *(v8s*)&sm.u1.t1[9600] = z;
    }
    __syncthreads();

    // ---- phase 2: tb = rbf1(conv2(t1)) on 16x16 (origin y0-4, x0-4), LDS only ----
    int lane = tid & 63, wv_ = tid >> 6;
    int p = lane & 15, q = lane >> 4;
    v4f a0[4], a1[4];
    #pragma unroll
    for (int g = 0; g < 4; ++g) { a0[g] = (v4f){0.f,0.f,0.f,0.f}; a1[g] = (v4f){0.f,0.f,0.f,0.f}; }
    #pragma unroll
    for (int s = 0; s < KSTEPS; ++s) {
        const int u = s / 5, v = s % 5;    // compile-time under full unroll
        v8s af0 = abuf[s * 64 + lane];
        v8s af1 = abuf[1600 + s * 64 + lane];
        #pragma unroll
        for (int g = 0; g < 4; ++g) {
            int row = wv_ * 4 + g;         // wave owns 4 rows of the 16x16 tile
            v8s b = *(const v8s*)&sm.u1.t1[((row + u) * 20 + (p + v)) * 24 + q * 8];
            a0[g] = __builtin_amdgcn_mfma_f32_16x16x32_bf16(af0, b, a0[g], 0, 0, 0);
            a1[g] = __builtin_amdgcn_mfma_f32_16x16x32_bf16(af1, b, a1[g], 0, 0, 0);
        }
    }
    #pragma unroll
    for (int g = 0; g < 4; ++g) {
        int row = wv_ * 4 + g;
        int gy = y0 - 4 + row, gx = x0 - 4 + p;
        bool inimg = (gy >= 0 && gy < H && gx >= 0 && gx < W);
        v4s st;
        #pragma unroll
        for (int j = 0; j < 4; ++j)
            st[j] = inimg ? f2bf(rbf_eval<false>(a0[g][j], sm.ws1 + (q * 4 + j) * NK, ctx)) : (short)0;
        *(v4s*)&sm.u2.tbt[(row * 16 + p) * 24 + q * 4] = st;
        if (q < 2) {
            #pragma unroll
            for (int j = 0; j < 4; ++j)
                st[j] = inimg ? f2bf(rbf_eval<false>(a1[g][j], sm.ws1 + (16 + q * 4 + j) * NK, ctx)) : (short)0;
            *(v4s*)&sm.u2.tbt[(row * 16 + p) * 24 + 16 + q * 4] = st;
        }
    }
    if (tid == 0) {   // zero pad after tbt
        v8s z = {0,0,0,0,0,0,0,0};
        *(v8s*)&sm.u2.tbt[6144] = z;
    }
    __syncthreads();

    // ---- phase 3: t3 = rbf'(convT2(tb)) on 12x12 (origin y0-2, x0-2) ----
    // waves 0..2 own 3 N-tiles each (9 x 16 = 144 px exactly); wave 3 idles
    if (wv_ < 3) {
        const v8s* ap = abuf + 3200;       // mode-1 fragments
        int base[3], frow[3], fcol[3];
        #pragma unroll
        for (int g = 0; g < 3; ++g) {
            int f = (wv_ * 3 + g) * 16 + p;
            int r_ = (f * 5462) >> 16;     // f / 12
            frow[g] = r_; fcol[g] = f - r_ * 12;
            base[g] = (r_ * 16 + fcol[g]) * 24 + q * 8;
        }
        v4f c0[3], c1[3];
        #pragma unroll
        for (int g = 0; g < 3; ++g) { c0[g] = (v4f){0.f,0.f,0.f,0.f}; c1[g] = (v4f){0.f,0.f,0.f,0.f}; }
        #pragma unroll
        for (int s = 0; s < KSTEPS; ++s) {
            const int off = ((s / 5) * 16 + (s % 5)) * 24;
            v8s af0 = ap[s * 64 + lane];
            v8s af1 = ap[1600 + s * 64 + lane];
            #pragma unroll
            for (int g = 0; g < 3; ++g) {
                v8s b = *(const v8s*)&sm.u2.tbt[base[g] + off];
                c0[g] = __builtin_amdgcn_mfma_f32_16x16x32_bf16(af0, b, c0[g], 0, 0, 0);
                c1[g] = __builtin_amdgcn_mfma_f32_16x16x32_bf16(af1, b, c1[g], 0, 0, 0);
            }
        }
        #pragma unroll
        for (int g = 0; g < 3; ++g) {
            int f = (wv_ * 3 + g) * 16 + p;
            int gy = y0 + frow[g] - 2, gx = x0 + fcol[g] - 2;
            bool inimg = (gy >= 0 && gy < H && gx >= 0 && gx < W);
            #pragma unroll
            for (int j = 0; j < 4; ++j)
                sm.u1.t3[f * T3S + q * 4 + j] =
                    inimg ? rbf_eval<true>(c0[g][j], sm.ws0 + (q * 4 + j) * NK, ctx) : 0.f;
            if (q < 2) {
                #pragma unroll
                for (int j = 0; j < 4; ++j)
                    sm.u1.t3[f * T3S + 16 + q * 4 + j] =
                        inimg ? rbf_eval<true>(c1[g][j], sm.ws0 + (16 + q * 4 + j) * NK, ctx) : 0.f;
            }
        }
    }
    __syncthreads();

    // ---- phase 4: convT1 (24->1) + final combine; 4-way channel split ----
    float* red = sm.ws1;                   // ws1 dead; 1 KB reduction buffer
    int gq = __builtin_amdgcn_readfirstlane(tid >> 6);
    int px = tid & 63, pr = px >> 3, pc = px & 7;
    float a = 0.f;
    #pragma unroll 1
    for (int cp = 0; cp < 3; ++cp) {
        int c = gq * 6 + cp * 2;
        const float* fb0 = f0t + c * 25;
        const float* fb1 = f0t + (c + 1) * 25;
        #pragma unroll
        for (int u = 0; u < 5; ++u)
            #pragma unroll
            for (int v = 0; v < 5; ++v) {
                float2 tp = *(const float2*)&sm.u1.t3[((pr + u) * 12 + (pc + v)) * T3S + c];
                a = fmaf(tp.x, fb0[u * 5 + v], a);
                a = fmaf(tp.y, fb1[u * 5 + v], a);
            }
    }
    red[tid] = a;
    __syncthreads();
    if (tid < 64) {
        float tot = red[tid] + red[64 + tid] + red[128 + tid] + red[192 + tid];
        int pix = (y0 + pr) * W + (x0 + pc);
        float elam = __expf(lamp[0]);
        float xv = x[pix], yv = y[pix];
        out[pix] = xv - (tot + elam * (xv - yv));
    }
}

extern "C" void kernel_launch(void* const* d_in, const int* in_sizes, int n_in,
                              void* d_out, int out_size, void* d_ws, size_t ws_size,
                              hipStream_t stream) {
    const float* x    = (const float*)d_in[0];
    const float* y    = (const float*)d_in[1];
    const float* f0   = (const float*)d_in[3];
    const float* f1   = (const float*)d_in[4];
    const float* aw0  = (const float*)d_in[5];
    const float* aw1  = (const float*)d_in[6];
    const float* mean = (const float*)d_in[7];
    const float* lamp = (const float*)d_in[8];
    float* out = (float*)d_out;

    float* w   = (float*)d_ws;
    float* f0n = w;                  // 600
    float* f0t = w + 640;            // 600
    v8s*  abuf = (v8s*)(w + 1536);   // 6400 * 16 B

    k_prep<<<25, 256, 0, stream>>>(f0, f1, f0n, f0t, abuf);
    k_main<<<1024, 256, 0, stream>>>(x, y, f0n, f0t, abuf, mean, aw0, aw1, lamp, out);
}

// Round 12
// 65.953 us; speedup vs baseline: 7.0370x; 1.4891x over previous
//
#include <hip/hip_runtime.h>
#include <math.h>

#define H 256
#define W 256
#define HW (H * W)
#define CH 24
#define NK 63
#define KSTEPS 25       // K = 25 taps * 32 (24 ch + 8 zero-pad in A-frags)
#define NE 257          // table dwords per channel (pairs of 258 samples)
#define TBLN (CH * NE)  // 6168 dwords per table
#define T3S 26          // t3 per-pixel stride in floats

typedef short v8s __attribute__((ext_vector_type(8)));
typedef short v4s __attribute__((ext_vector_type(4)));
typedef float v4f __attribute__((ext_vector_type(4)));

// ---------------- bf16 helpers --------------------------------------------------
__device__ __forceinline__ short f2bf(float v) {
    unsigned u = __float_as_uint(v);
    u += 0x7fff + ((u >> 16) & 1);
    return (short)(u >> 16);
}

// ---------------- table lookup ctx ----------------------------------------------
struct TblCtx { float off, invh; };
__device__ __forceinline__ TblCtx make_tctx(const float* __restrict__ mean) {
    TblCtx c;
    float lo = mean[0] - 12.f;
    float hi = mean[NK - 1] + 12.f;
    c.invh = 257.f / (hi - lo);
    c.off  = -lo * c.invh;
    return c;
}
// piecewise-linear eval from paired-bf16 table (1 LDS dword read)
__device__ __forceinline__ float tbl_eval(const unsigned* __restrict__ tbl, int ch,
                                          float v, const TblCtx& c) {
    float t = fmaf(v, c.invh, c.off);
    t = fminf(fmaxf(t, 0.f), 256.999f);
    float fi = floorf(t);
    float fr = t - fi;
    unsigned u = tbl[ch * NE + (int)fi];
    float a = __uint_as_float(u << 16);
    float b = __uint_as_float(u & 0xffff0000u);
    return fmaf(fr, b - a, a);
}

// ---------------- prep: norms, f0n/f0t, A-frag pack, RBF tables ------------------
// abuf: [mode 2][mtile 2][kstep 25][lane 64] v8s. k = tap*32 + c (c<24, pad=0).
// tables: Tg[tt][ch][NE], tt: 0=rbf(aw0), 1=rbf(aw1), 2=rbf_der(aw0); exact 63-tap.
__global__ void k_prep(const float* __restrict__ f0, const float* __restrict__ f1,
                       const float* __restrict__ mean, const float* __restrict__ aw0,
                       const float* __restrict__ aw1,
                       float* __restrict__ f0n, float* __restrict__ f0t,
                       v8s* __restrict__ abuf, unsigned* __restrict__ tg) {
    __shared__ float red[256];
    int tid = threadIdx.x;
    float s1 = 0.f;
    for (int i = tid; i < 14400; i += 256) s1 += f1[i] * f1[i];
    red[tid] = s1; __syncthreads();
    for (int off = 128; off; off >>= 1) { if (tid < off) red[tid] += red[tid + off]; __syncthreads(); }
    float inv1 = 1.f / sqrtf(red[0]);
    __syncthreads();
    if (blockIdx.x == 0) {
        float s0 = 0.f;
        for (int i = tid; i < 600; i += 256) s0 += f0[i] * f0[i];
        red[tid] = s0; __syncthreads();
        for (int off = 128; off; off >>= 1) { if (tid < off) red[tid] += red[tid + off]; __syncthreads(); }
        float inv0 = 1.f / sqrtf(red[0]);
        for (int i = tid; i < 600; i += 256) {
            int c = i / 25, k = i % 25;
            f0n[i] = f0[i] * inv0;
            f0t[i] = f0[c * 25 + (24 - k)] * inv0;
        }
    }
    // A-fragment pack: 6400 jobs
    int gid = blockIdx.x * 256 + tid;
    {
        int lane = gid & 63;
        int rest = gid >> 6;               // 0..99
        int s = rest % KSTEPS;
        int md = rest / KSTEPS;            // 0..3
        int mode = md >> 1, m = md & 1;
        int o = m * 16 + (lane & 15);
        v8s av;
        #pragma unroll
        for (int j = 0; j < 8; ++j) {
            int c = 8 * (lane >> 4) + j;
            float wv = 0.f;
            if (o < CH && c < CH) {
                wv = (mode == 0) ? f1[(o * CH + c) * 25 + s]
                                 : f1[(c * CH + o) * 25 + (24 - s)];
                wv *= inv1;
            }
            av[j] = f2bf(wv);
        }
        abuf[gid] = av;
    }
    // RBF tables: 3 * 6168 dwords; exact 63-tap sums at two samples per dword
    float lo = mean[0] - 12.f;
    float hi = mean[NK - 1] + 12.f;
    float h  = (hi - lo) * (1.f / 257.f);
    for (int j = gid; j < 3 * TBLN; j += 6400) {
        int tt = j / TBLN;
        int rest = j - tt * TBLN;
        int ch = rest / NE;
        int i  = rest - ch * NE;
        const float* wr = ((tt == 1) ? aw1 : aw0) + ch * NK;
        float v0 = fmaf(h, (float)i, lo);
        float v1 = v0 + h;
        float s0 = 0.f, s1v = 0.f;
        for (int k = 0; k < NK; ++k) {
            float m = mean[k], wk = wr[k];
            float d0 = v0 - m, d1 = v1 - m;
            float e0 = __expf(d0 * d0 * -0.005f);
            float e1 = __expf(d1 * d1 * -0.005f);
            if (tt == 2) { e0 *= d0 * -0.01f; e1 *= d1 * -0.01f; }
            s0 = fmaf(e0, wk, s0);
            s1v = fmaf(e1, wk, s1v);
        }
        unsigned pb = ((unsigned)(unsigned short)f2bf(s1v) << 16)
                    | (unsigned)(unsigned short)f2bf(s0);
        tg[j] = pb;
    }
}

// ---------------- fused A: conv1+rbf0 -> conv2 MFMA + rbf1 -----------------------
// 8x8 output tile, 1024 blocks, 4 blocks/CU. t1: 12x12 halo tile, ch-minor bf16.
// tb out: [HW][24] bf16. Table buffer staged with T0, re-staged with T1 mid-kernel.
__global__ __launch_bounds__(256, 4) void k_fuseA(const float* __restrict__ x,
        const float* __restrict__ f0n, const v8s* __restrict__ abuf,
        const float* __restrict__ mean, const unsigned* __restrict__ T0g,
        const unsigned* __restrict__ T1g, short* __restrict__ tb) {
    __shared__ float xs[256];
    __shared__ unsigned tbl[TBLN];
    __shared__ __align__(16) short t1[144 * 24 + 8];
    int tid = threadIdx.x;
    int x0 = blockIdx.x * 8, y0 = blockIdx.y * 8;
    {   // stage x window (16x16, clamped = replication pad)
        int r = tid >> 4, cL = tid & 15;
        int gy = min(max(y0 + r - 4, 0), H - 1);
        int gx = min(max(x0 + cL - 4, 0), W - 1);
        xs[tid] = x[gy * W + gx];
    }
    for (int i = tid; i < TBLN; i += 256) tbl[i] = T0g[i];
    TblCtx ctx = make_tctx(mean);
    __syncthreads();

    // stage 1: t1 = rbf0(conv1) on 12x12 haloed region
    if (tid < 144) {
        int yi = (tid * 5462) >> 16;        // tid / 12
        int xi = tid - yi * 12;
        int sy = min(max(y0 + yi - 2, 0), H - 1);
        int sx = min(max(x0 + xi - 2, 0), W - 1);
        int iy[5], ix[5];
        #pragma unroll
        for (int u = 0; u < 5; ++u) {
            iy[u] = min(max(sy + u - 2, 0), H - 1) - (y0 - 4);
            ix[u] = min(max(sx + u - 2, 0), W - 1) - (x0 - 4);
        }
        float in_[25];
        #pragma unroll
        for (int u = 0; u < 5; ++u)
            #pragma unroll
            for (int v = 0; v < 5; ++v) in_[u * 5 + v] = xs[iy[u] * 16 + ix[v]];
        #pragma unroll 1
        for (int og = 0; og < 3; ++og) {
            v8s pk;
            #pragma unroll
            for (int oj = 0; oj < 8; ++oj) {
                int o = og * 8 + oj;
                float a = 0.f;
                #pragma unroll
                for (int k = 0; k < 25; ++k) a = fmaf(in_[k], f0n[o * 25 + k], a);
                pk[oj] = f2bf(tbl_eval(tbl, o, a, ctx));
            }
            *(v8s*)&t1[tid * 24 + og * 8] = pk;
        }
    }
    if (tid == 0) {   // zero pad (q=3 stray B-reads of last pixel must be finite)
        v8s z = {0,0,0,0,0,0,0,0};
        *(v8s*)&t1[3456] = z;
    }
    __syncthreads();

    // re-stage table with T1 (epilogue weights); MFMA below doesn't touch tbl
    for (int i = tid; i < TBLN; i += 256) tbl[i] = T1g[i];

    // conv2 MFMA; wave = one 16-px N-tile (2 rows of 8)
    int lane = tid & 63, wv_ = tid >> 6;
    int p = lane & 15, q = lane >> 4;
    int row = (wv_ * 16 + p) >> 3, col = p & 7;
    const short* bbase = &t1[(row * 12 + col) * 24 + q * 8];
    v4f a0v = {0.f,0.f,0.f,0.f}, a1v = {0.f,0.f,0.f,0.f};
    #pragma unroll
    for (int s = 0; s < KSTEPS; ++s) {
        const int u = s / 5, v = s % 5;     // compile-time under full unroll
        v8s b   = *(const v8s*)&bbase[(u * 12 + v) * 24];
        v8s af0 = abuf[s * 64 + lane];
        v8s af1 = abuf[1600 + s * 64 + lane];
        a0v = __builtin_amdgcn_mfma_f32_16x16x32_bf16(af0, b, a0v, 0, 0, 0);
        a1v = __builtin_amdgcn_mfma_f32_16x16x32_bf16(af1, b, a1v, 0, 0, 0);
    }
    __syncthreads();   // T1 fully staged; epilogue lookups below

    int pix = (y0 + row) * W + (x0 + col);
    v4s st;
    #pragma unroll
    for (int j = 0; j < 4; ++j)
        st[j] = f2bf(tbl_eval(tbl, q * 4 + j, a0v[j], ctx));
    *(v4s*)&tb[pix * 24 + q * 4] = st;
    if (q < 2) {
        #pragma unroll
        for (int j = 0; j < 4; ++j)
            st[j] = f2bf(tbl_eval(tbl, 16 + q * 4 + j, a1v[j], ctx));
        *(v4s*)&tb[pix * 24 + 16 + q * 4] = st;
    }
}

// ---------------- fused B: convT2 MFMA + rbf'(table) -> convT1 + final -----------
// 8x8 output tile, 1024 blocks, 3 blocks/CU. tbt: 16x16 window (zero pad), ch-minor.
__global__ __launch_bounds__(256, 3) void k_fuseB(const short* __restrict__ tb,
        const v8s* __restrict__ abuf, const float* __restrict__ f0t,
        const float* __restrict__ mean, const unsigned* __restrict__ TDg,
        const float* __restrict__ x, const float* __restrict__ y,
        const float* __restrict__ lamp, float* __restrict__ out) {
    __shared__ __align__(16) short tbt[256 * 24 + 8];  // reused as red[] in phase4
    __shared__ unsigned tbl[TBLN];
    __shared__ float t3[144 * T3S];
    int tid = threadIdx.x;
    int x0 = blockIdx.x * 8, y0 = blockIdx.y * 8;
    {   // stage tb window: 16x16 px, zero pad outside image
        int r = tid >> 4, cL = tid & 15;
        int gy = y0 + r - 4, gx = x0 + cL - 4;
        v8s z = {0,0,0,0,0,0,0,0};
        if (gy >= 0 && gy < H && gx >= 0 && gx < W) {
            const v8s* src = (const v8s*)&tb[(gy * W + gx) * 24];
            *(v8s*)&tbt[tid * 24]      = src[0];
            *(v8s*)&tbt[tid * 24 + 8]  = src[1];
            *(v8s*)&tbt[tid * 24 + 16] = src[2];
        } else {
            *(v8s*)&tbt[tid * 24]      = z;
            *(v8s*)&tbt[tid * 24 + 8]  = z;
            *(v8s*)&tbt[tid * 24 + 16] = z;
        }
        if (tid == 0) *(v8s*)&tbt[6144] = z;   // zero pad
    }
    for (int i = tid; i < TBLN; i += 256) tbl[i] = TDg[i];
    TblCtx ctx = make_tctx(mean);
    __syncthreads();

    // convT2 MFMA (mode-1 A-frags): waves 0..2 own 3 N-tiles each (9x16 = 144 px)
    int lane = tid & 63, wv_ = tid >> 6;
    int p = lane & 15, q = lane >> 4;
    if (wv_ < 3) {
        const v8s* ap = abuf + 3200;
        int base[3], frow[3], fcol[3];
        #pragma unroll
        for (int g = 0; g < 3; ++g) {
            int f = (wv_ * 3 + g) * 16 + p;     // flat t3 px < 144
            int r_ = (f * 5462) >> 16;          // f / 12
            frow[g] = r_; fcol[g] = f - r_ * 12;
            base[g] = (r_ * 16 + fcol[g]) * 24 + q * 8;
        }
        v4f c0[3], c1[3];
        #pragma unroll
        for (int g = 0; g < 3; ++g) { c0[g] = (v4f){0.f,0.f,0.f,0.f}; c1[g] = (v4f){0.f,0.f,0.f,0.f}; }
        #pragma unroll
        for (int s = 0; s < KSTEPS; ++s) {
            const int off = ((s / 5) * 16 + (s % 5)) * 24;
            v8s af0 = ap[s * 64 + lane];
            v8s af1 = ap[1600 + s * 64 + lane];
            #pragma unroll
            for (int g = 0; g < 3; ++g) {
                v8s b = *(const v8s*)&tbt[base[g] + off];
                c0[g] = __builtin_amdgcn_mfma_f32_16x16x32_bf16(af0, b, c0[g], 0, 0, 0);
                c1[g] = __builtin_amdgcn_mfma_f32_16x16x32_bf16(af1, b, c1[g], 0, 0, 0);
            }
        }
        // rbf_der via table -> t3 (zero outside image)
        #pragma unroll
        for (int g = 0; g < 3; ++g) {
            int f = (wv_ * 3 + g) * 16 + p;
            int gy = y0 + frow[g] - 2, gx = x0 + fcol[g] - 2;
            bool inimg = (gy >= 0 && gy < H && gx >= 0 && gx < W);
            #pragma unroll
            for (int j = 0; j < 4; ++j)
                t3[f * T3S + q * 4 + j] =
                    inimg ? tbl_eval(tbl, q * 4 + j, c0[g][j], ctx) : 0.f;
            if (q < 2) {
                #pragma unroll
                for (int j = 0; j < 4; ++j)
                    t3[f * T3S + 16 + q * 4 + j] =
                        inimg ? tbl_eval(tbl, 16 + q * 4 + j, c1[g][j], ctx) : 0.f;
            }
        }
    }
    __syncthreads();   // tbt fully consumed; reuse as reduction buffer

    // convT1 (24->1, pre-flipped f0t) + final; 4-way channel split across waves
    float* red = (float*)tbt;
    int gq = __builtin_amdgcn_readfirstlane(tid >> 6);
    int px = tid & 63, pr = px >> 3, pc = px & 7;
    float a = 0.f;
    #pragma unroll 1
    for (int cp = 0; cp < 3; ++cp) {
        int c = gq * 6 + cp * 2;               // even -> 8B-aligned float2
        const float* fb0 = f0t + c * 25;
        const float* fb1 = f0t + (c + 1) * 25;
        #pragma unroll
        for (int u = 0; u < 5; ++u)
            #pragma unroll
            for (int v = 0; v < 5; ++v) {
                float2 tp = *(const float2*)&t3[((pr + u) * 12 + (pc + v)) * T3S + c];
                a = fmaf(tp.x, fb0[u * 5 + v], a);
                a = fmaf(tp.y, fb1[u * 5 + v], a);
            }
    }
    red[tid] = a;
    __syncthreads();
    if (tid < 64) {
        float tot = red[tid] + red[64 + tid] + red[128 + tid] + red[192 + tid];
        int pix = (y0 + pr) * W + (x0 + pc);
        float elam = __expf(lamp[0]);
        float xv = x[pix], yv = y[pix];
        out[pix] = xv - (tot + elam * (xv - yv));
    }
}

extern "C" void kernel_launch(void* const* d_in, const int* in_sizes, int n_in,
                              void* d_out, int out_size, void* d_ws, size_t ws_size,
                              hipStream_t stream) {
    const float* x    = (const float*)d_in[0];
    const float* y    = (const float*)d_in[1];
    const float* f0   = (const float*)d_in[3];
    const float* f1   = (const float*)d_in[4];
    const float* aw0  = (const float*)d_in[5];
    const float* aw1  = (const float*)d_in[6];
    const float* mean = (const float*)d_in[7];
    const float* lamp = (const float*)d_in[8];
    float* out = (float*)d_out;

    float* w   = (float*)d_ws;
    float* f0n = w;                          // 600
    float* f0t = w + 640;                    // 600
    v8s*  abuf = (v8s*)(w + 1536);           // 6400*16B -> ends at w+27136
    unsigned* tg = (unsigned*)(w + 27136);   // 3*6168 dwords -> ends at w+45640
    unsigned* T0g = tg;
    unsigned* T1g = tg + TBLN;
    unsigned* TDg = tg + 2 * TBLN;
    short* tb  = (short*)(w + 46080);        // 1.57M shorts

    k_prep<<<25, 256, 0, stream>>>(f0, f1, mean, aw0, aw1, f0n, f0t, abuf, tg);
    dim3 grid(W / 8, H / 8);                 // 32 x 32 = 1024 blocks
    k_fuseA<<<grid, 256, 0, stream>>>(x, f0n, abuf, mean, T0g, T1g, tb);
    k_fuseB<<<grid, 256, 0, stream>>>(tb, abuf, f0t, mean, TDg, x, y, lamp, out);
}

// Round 13
// 64.358 us; speedup vs baseline: 7.2115x; 1.0248x over previous
//
#include <hip/hip_runtime.h>
#include <math.h>

#define H 256
#define W 256
#define HW (H * W)
#define CH 24
#define NK 63
#define KSTEPS 25       // K = 25 taps * 32 (24 ch + 8 zero-pad in A-frags)
#define NE 257          // table dwords per channel (pairs of 258 samples)
#define TBLN (CH * NE)  // 6168 dwords per table
#define T3S 26          // t3 per-pixel stride in floats

typedef short v8s __attribute__((ext_vector_type(8)));
typedef short v4s __attribute__((ext_vector_type(4)));
typedef float v4f __attribute__((ext_vector_type(4)));

// ---------------- bf16 helpers --------------------------------------------------
__device__ __forceinline__ short f2bf(float v) {
    unsigned u = __float_as_uint(v);
    u += 0x7fff + ((u >> 16) & 1);
    return (short)(u >> 16);
}

// ---------------- table lookup (global, L1-resident; no LDS staging) -------------
struct TblCtx { float off, invh; };
__device__ __forceinline__ TblCtx make_tctx(const float* __restrict__ mean) {
    TblCtx c;
    float lo = mean[0] - 12.f;
    float hi = mean[NK - 1] + 12.f;
    c.invh = 257.f / (hi - lo);
    c.off  = -lo * c.invh;
    return c;
}
__device__ __forceinline__ float tbl_eval(const unsigned* __restrict__ tbl, int ch,
                                          float v, const TblCtx& c) {
    float t = fmaf(v, c.invh, c.off);
    t = fminf(fmaxf(t, 0.f), 256.999f);
    float fi = floorf(t);
    float fr = t - fi;
    unsigned u = tbl[ch * NE + (int)fi];        // global dword, L1-hit
    float a = __uint_as_float(u << 16);
    float b = __uint_as_float(u & 0xffff0000u);
    return fmaf(fr, b - a, a);
}

// ---------------- prep: norms, f0n/f0t, A-frag pack, RBF tables ------------------
// abuf: [mode 2][mtile 2][kstep 25][lane 64] v8s. k = tap*32 + c (c<24, pad=0).
// tables: tg[tt][ch][NE], tt: 0=rbf(aw0), 1=rbf(aw1), 2=rbf_der(aw0); exact 63-tap.
__global__ void k_prep(const float* __restrict__ f0, const float* __restrict__ f1,
                       const float* __restrict__ mean, const float* __restrict__ aw0,
                       const float* __restrict__ aw1,
                       float* __restrict__ f0n, float* __restrict__ f0t,
                       v8s* __restrict__ abuf, unsigned* __restrict__ tg) {
    __shared__ float red[256];
    int tid = threadIdx.x;
    float s1 = 0.f;
    for (int i = tid; i < 14400; i += 256) s1 += f1[i] * f1[i];
    red[tid] = s1; __syncthreads();
    for (int off = 128; off; off >>= 1) { if (tid < off) red[tid] += red[tid + off]; __syncthreads(); }
    float inv1 = 1.f / sqrtf(red[0]);
    __syncthreads();
    if (blockIdx.x == 0) {
        float s0 = 0.f;
        for (int i = tid; i < 600; i += 256) s0 += f0[i] * f0[i];
        red[tid] = s0; __syncthreads();
        for (int off = 128; off; off >>= 1) { if (tid < off) red[tid] += red[tid + off]; __syncthreads(); }
        float inv0 = 1.f / sqrtf(red[0]);
        for (int i = tid; i < 600; i += 256) {
            int c = i / 25, k = i % 25;
            f0n[i] = f0[i] * inv0;
            f0t[i] = f0[c * 25 + (24 - k)] * inv0;
        }
    }
    // A-fragment pack: 6400 jobs
    int gid = blockIdx.x * 256 + tid;
    {
        int lane = gid & 63;
        int rest = gid >> 6;               // 0..99
        int s = rest % KSTEPS;
        int md = rest / KSTEPS;            // 0..3
        int mode = md >> 1, m = md & 1;
        int o = m * 16 + (lane & 15);
        v8s av;
        #pragma unroll
        for (int j = 0; j < 8; ++j) {
            int c = 8 * (lane >> 4) + j;
            float wv = 0.f;
            if (o < CH && c < CH) {
                wv = (mode == 0) ? f1[(o * CH + c) * 25 + s]
                                 : f1[(c * CH + o) * 25 + (24 - s)];
                wv *= inv1;
            }
            av[j] = f2bf(wv);
        }
        abuf[gid] = av;
    }
    // RBF tables: 3 * 6168 dwords; exact 63-tap sums, two samples per dword
    float lo = mean[0] - 12.f;
    float hi = mean[NK - 1] + 12.f;
    float h  = (hi - lo) * (1.f / 257.f);
    for (int j = gid; j < 3 * TBLN; j += 6400) {
        int tt = j / TBLN;
        int rest = j - tt * TBLN;
        int ch = rest / NE;
        int i  = rest - ch * NE;
        const float* wr = ((tt == 1) ? aw1 : aw0) + ch * NK;
        float v0 = fmaf(h, (float)i, lo);
        float v1 = v0 + h;
        float s0 = 0.f, s1v = 0.f;
        for (int k = 0; k < NK; ++k) {
            float m = mean[k], wk = wr[k];
            float d0 = v0 - m, d1 = v1 - m;
            float e0 = __expf(d0 * d0 * -0.005f);
            float e1 = __expf(d1 * d1 * -0.005f);
            if (tt == 2) { e0 *= d0 * -0.01f; e1 *= d1 * -0.01f; }
            s0 = fmaf(e0, wk, s0);
            s1v = fmaf(e1, wk, s1v);
        }
        unsigned pb = ((unsigned)(unsigned short)f2bf(s1v) << 16)
                    | (unsigned)(unsigned short)f2bf(s0);
        tg[j] = pb;
    }
}

// ---------------- fused A: conv1+rbf0(T0) -> conv2 MFMA + rbf1(T1) ---------------
// 8x8 output tile, 1024 blocks, 4 blocks/CU. LDS: xs 1KB + t1 7KB. Tables global.
__global__ __launch_bounds__(256, 4) void k_fuseA(const float* __restrict__ x,
        const float* __restrict__ f0n, const v8s* __restrict__ abuf,
        const float* __restrict__ mean, const unsigned* __restrict__ T0g,
        const unsigned* __restrict__ T1g, short* __restrict__ tb) {
    __shared__ float xs[256];
    __shared__ __align__(16) short t1[144 * 24 + 8];
    int tid = threadIdx.x;
    int x0 = blockIdx.x * 8, y0 = blockIdx.y * 8;
    {   // stage x window (16x16, clamped = replication pad)
        int r = tid >> 4, cL = tid & 15;
        int gy = min(max(y0 + r - 4, 0), H - 1);
        int gx = min(max(x0 + cL - 4, 0), W - 1);
        xs[tid] = x[gy * W + gx];
    }
    TblCtx ctx = make_tctx(mean);
    __syncthreads();

    // stage 1: t1 = rbf0(conv1) on 12x12; 432 jobs = (og 0..2, px 0..143)
    #pragma unroll
    for (int r = 0; r < 2; ++r) {
        int jb = tid + r * 256;
        if (jb < 432) {
            int og = (jb * 456) >> 16;      // jb / 144
            int px = jb - og * 144;
            int yi = (px * 5462) >> 16;     // px / 12
            int xi = px - yi * 12;
            int sy = min(max(y0 + yi - 2, 0), H - 1);
            int sx = min(max(x0 + xi - 2, 0), W - 1);
            int iy[5], ix[5];
            #pragma unroll
            for (int u = 0; u < 5; ++u) {
                iy[u] = min(max(sy + u - 2, 0), H - 1) - (y0 - 4);
                ix[u] = min(max(sx + u - 2, 0), W - 1) - (x0 - 4);
            }
            float in_[25];
            #pragma unroll
            for (int u = 0; u < 5; ++u)
                #pragma unroll
                for (int v = 0; v < 5; ++v) in_[u * 5 + v] = xs[iy[u] * 16 + ix[v]];
            v8s pk;
            #pragma unroll
            for (int oj = 0; oj < 8; ++oj) {
                int o = og * 8 + oj;
                float a = 0.f;
                #pragma unroll
                for (int k = 0; k < 25; ++k) a = fmaf(in_[k], f0n[o * 25 + k], a);
                pk[oj] = f2bf(tbl_eval(T0g, o, a, ctx));
            }
            *(v8s*)&t1[px * 24 + og * 8] = pk;
        }
    }
    if (tid == 0) {   // zero pad (q=3 stray B-reads of last pixel must be finite)
        v8s z = {0,0,0,0,0,0,0,0};
        *(v8s*)&t1[3456] = z;
    }
    __syncthreads();

    // conv2 MFMA; wave = one 16-px N-tile (2 rows of 8)
    int lane = tid & 63, wv_ = tid >> 6;
    int p = lane & 15, q = lane >> 4;
    int row = (wv_ * 16 + p) >> 3, col = p & 7;
    const short* bbase = &t1[(row * 12 + col) * 24 + q * 8];
    v4f a0v = {0.f,0.f,0.f,0.f}, a1v = {0.f,0.f,0.f,0.f};
    #pragma unroll
    for (int s = 0; s < KSTEPS; ++s) {
        const int u = s / 5, v = s % 5;     // compile-time under full unroll
        v8s b   = *(const v8s*)&bbase[(u * 12 + v) * 24];
        v8s af0 = abuf[s * 64 + lane];
        v8s af1 = abuf[1600 + s * 64 + lane];
        a0v = __builtin_amdgcn_mfma_f32_16x16x32_bf16(af0, b, a0v, 0, 0, 0);
        a1v = __builtin_amdgcn_mfma_f32_16x16x32_bf16(af1, b, a1v, 0, 0, 0);
    }
    // epilogue: rbf1 via T1 (global) -> tb[pix][ch], 8B stores
    int pix = (y0 + row) * W + (x0 + col);
    v4s st;
    #pragma unroll
    for (int j = 0; j < 4; ++j)
        st[j] = f2bf(tbl_eval(T1g, q * 4 + j, a0v[j], ctx));
    *(v4s*)&tb[pix * 24 + q * 4] = st;
    if (q < 2) {
        #pragma unroll
        for (int j = 0; j < 4; ++j)
            st[j] = f2bf(tbl_eval(T1g, 16 + q * 4 + j, a1v[j], ctx));
        *(v4s*)&tb[pix * 24 + 16 + q * 4] = st;
    }
}

// ---------------- fused B: convT2 MFMA + rbf'(TD) -> convT1 + final --------------
// 8x8 output tile, 1024 blocks, 4 blocks/CU. LDS: tbt 12KB + t3 15KB.
__global__ __launch_bounds__(256, 4) void k_fuseB(const short* __restrict__ tb,
        const v8s* __restrict__ abuf, const float* __restrict__ f0t,
        const float* __restrict__ mean, const unsigned* __restrict__ TDg,
        const float* __restrict__ x, const float* __restrict__ y,
        const float* __restrict__ lamp, float* __restrict__ out) {
    __shared__ __align__(16) short tbt[256 * 24 + 8];  // reused as red[] in phase4
    __shared__ float t3[144 * T3S];
    int tid = threadIdx.x;
    int x0 = blockIdx.x * 8, y0 = blockIdx.y * 8;
    {   // stage tb window: 16x16 px, zero pad outside image
        int r = tid >> 4, cL = tid & 15;
        int gy = y0 + r - 4, gx = x0 + cL - 4;
        v8s z = {0,0,0,0,0,0,0,0};
        if (gy >= 0 && gy < H && gx >= 0 && gx < W) {
            const v8s* src = (const v8s*)&tb[(gy * W + gx) * 24];
            *(v8s*)&tbt[tid * 24]      = src[0];
            *(v8s*)&tbt[tid * 24 + 8]  = src[1];
            *(v8s*)&tbt[tid * 24 + 16] = src[2];
        } else {
            *(v8s*)&tbt[tid * 24]      = z;
            *(v8s*)&tbt[tid * 24 + 8]  = z;
            *(v8s*)&tbt[tid * 24 + 16] = z;
        }
        if (tid == 0) *(v8s*)&tbt[6144] = z;   // zero pad
    }
    TblCtx ctx = make_tctx(mean);
    __syncthreads();

    // convT2 MFMA (mode-1 A-frags): waves 0..2 own 3 N-tiles each (9x16 = 144 px)
    int lane = tid & 63, wv_ = tid >> 6;
    int p = lane & 15, q = lane >> 4;
    if (wv_ < 3) {
        const v8s* ap = abuf + 3200;
        int base[3], frow[3], fcol[3];
        #pragma unroll
        for (int g = 0; g < 3; ++g) {
            int f = (wv_ * 3 + g) * 16 + p;     // flat t3 px < 144
            int r_ = (f * 5462) >> 16;          // f / 12
            frow[g] = r_; fcol[g] = f - r_ * 12;
            base[g] = (r_ * 16 + fcol[g]) * 24 + q * 8;
        }
        v4f c0[3], c1[3];
        #pragma unroll
        for (int g = 0; g < 3; ++g) { c0[g] = (v4f){0.f,0.f,0.f,0.f}; c1[g] = (v4f){0.f,0.f,0.f,0.f}; }
        #pragma unroll
        for (int s = 0; s < KSTEPS; ++s) {
            const int off = ((s / 5) * 16 + (s % 5)) * 24;
            v8s af0 = ap[s * 64 + lane];
            v8s af1 = ap[1600 + s * 64 + lane];
            #pragma unroll
            for (int g = 0; g < 3; ++g) {
                v8s b = *(const v8s*)&tbt[base[g] + off];
                c0[g] = __builtin_amdgcn_mfma_f32_16x16x32_bf16(af0, b, c0[g], 0, 0, 0);
                c1[g] = __builtin_amdgcn_mfma_f32_16x16x32_bf16(af1, b, c1[g], 0, 0, 0);
            }
        }
        // rbf_der via TD (global) -> t3 (zero outside image)
        #pragma unroll
        for (int g = 0; g < 3; ++g) {
            int f = (wv_ * 3 + g) * 16 + p;
            int gy = y0 + frow[g] - 2, gx = x0 + fcol[g] - 2;
            bool inimg = (gy >= 0 && gy < H && gx >= 0 && gx < W);
            #pragma unroll
            for (int j = 0; j < 4; ++j)
                t3[f * T3S + q * 4 + j] =
                    inimg ? tbl_eval(TDg, q * 4 + j, c0[g][j], ctx) : 0.f;
            if (q < 2) {
                #pragma unroll
                for (int j = 0; j < 4; ++j)
                    t3[f * T3S + 16 + q * 4 + j] =
                        inimg ? tbl_eval(TDg, 16 + q * 4 + j, c1[g][j], ctx) : 0.f;
            }
        }
    }
    __syncthreads();   // tbt fully consumed; reuse as reduction buffer

    // convT1 (24->1, pre-flipped f0t) + final; 4-way channel split across waves
    float* red = (float*)tbt;
    int gq = __builtin_amdgcn_readfirstlane(tid >> 6);
    int px = tid & 63, pr = px >> 3, pc = px & 7;
    float a = 0.f;
    #pragma unroll 1
    for (int cp = 0; cp < 3; ++cp) {
        int c = gq * 6 + cp * 2;               // even -> 8B-aligned float2
        const float* fb0 = f0t + c * 25;
        const float* fb1 = f0t + (c + 1) * 25;
        #pragma unroll
        for (int u = 0; u < 5; ++u)
            #pragma unroll
            for (int v = 0; v < 5; ++v) {
                float2 tp = *(const float2*)&t3[((pr + u) * 12 + (pc + v)) * T3S + c];
                a = fmaf(tp.x, fb0[u * 5 + v], a);
                a = fmaf(tp.y, fb1[u * 5 + v], a);
            }
    }
    red[tid] = a;
    __syncthreads();
    if (tid < 64) {
        float tot = red[tid] + red[64 + tid] + red[128 + tid] + red[192 + tid];
        int pix = (y0 + pr) * W + (x0 + pc);
        float elam = __expf(lamp[0]);
        float xv = x[pix], yv = y[pix];
        out[pix] = xv - (tot + elam * (xv - yv));
    }
}

extern "C" void kernel_launch(void* const* d_in, const int* in_sizes, int n_in,
                              void* d_out, int out_size, void* d_ws, size_t ws_size,
                              hipStream_t stream) {
    const float* x    = (const float*)d_in[0];
    const float* y    = (const float*)d_in[1];
    const float* f0   = (const float*)d_in[3];
    const float* f1   = (const float*)d_in[4];
    const float* aw0  = (const float*)d_in[5];
    const float* aw1  = (const float*)d_in[6];
    const float* mean = (const float*)d_in[7];
    const float* lamp = (const float*)d_in[8];
    float* out = (float*)d_out;

    float* w   = (float*)d_ws;
    float* f0n = w;                          // 600
    float* f0t = w + 640;                    // 600
    v8s*  abuf = (v8s*)(w + 1536);           // 6400*16B -> ends at w+27136
    unsigned* tg = (unsigned*)(w + 27136);   // 3*6168 dwords -> ends at w+45640
    unsigned* T0g = tg;
    unsigned* T1g = tg + TBLN;
    unsigned* TDg = tg + 2 * TBLN;
    short* tb  = (short*)(w + 46080);        // 1.57M shorts

    k_prep<<<25, 256, 0, stream>>>(f0, f1, mean, aw0, aw1, f0n, f0t, abuf, tg);
    dim3 grid(W / 8, H / 8);                 // 32 x 32 = 1024 blocks
    k_fuseA<<<grid, 256, 0, stream>>>(x, f0n, abuf, mean, T0g, T1g, tb);
    k_fuseB<<<grid, 256, 0, stream>>>(tb, abuf, f0t, mean, TDg, x, y, lamp, out);
}